// Round 1
// baseline (436.640 us; speedup 1.0000x reference)
//
#include <hip/hip_runtime.h>
#include <hip/hip_bf16.h>
#include <cstdint>

#define Bsz 32
#define Dd 2048
#define Ff 512

typedef __attribute__((ext_vector_type(8))) short short8;
typedef __attribute__((ext_vector_type(4))) float floatx4;

__device__ inline unsigned short f2bf(float f) {
  union { float f; unsigned int u; } c; c.f = f;
  unsigned int u = c.u;
  return (unsigned short)((u + 0x7FFFu + ((u >> 16) & 1u)) >> 16);
}

__device__ inline void gld_lds16(const void* g, void* l) {
  __builtin_amdgcn_global_load_lds(
      (const __attribute__((address_space(1))) void*)g,
      (__attribute__((address_space(3))) void*)l,
      16, 0, 0);
}

// K1: abs_sum[j] = sum_k |s[j] - s[k]|, split over k-chunks, atomicAdd partials.
__global__ __launch_bounds__(256) void k_abs_sum(const float* __restrict__ s,
                                                 float* __restrict__ abs_sum) {
  __shared__ float sk[128];
  int t = threadIdx.x;
  int j = blockIdx.x * 256 + t;
  int k0 = blockIdx.y * 128;
  if (t < 128) sk[t] = s[k0 + t];
  __syncthreads();
  float sj = s[j];
  float acc = 0.f;
#pragma unroll 8
  for (int k = 0; k < 128; ++k) acc += fabsf(sj - sk[k]);
  atomicAdd(&abs_sum[j], acc);
}

// K2: one block per row i: logits -> softmax -> bf16 P[i][:]
__global__ __launch_bounds__(256) void k_softmax(const float* __restrict__ s,
                                                 const float* __restrict__ abs_sum,
                                                 unsigned short* __restrict__ P) {
  __shared__ float lg[Dd];
  __shared__ float redm[4];
  __shared__ float reds[4];
  int i = blockIdx.x, t = threadIdx.x;
  float scal = (float)(Dd - 1 - 2 * i);  // D+1-2*(i+1)
  float lmax = -3.4e38f;
  for (int j = t; j < Dd; j += 256) {
    float v = fmaf(scal, s[j], -abs_sum[j]);  // TAU = 1
    lg[j] = v;
    lmax = fmaxf(lmax, v);
  }
#pragma unroll
  for (int off = 32; off > 0; off >>= 1) lmax = fmaxf(lmax, __shfl_down(lmax, off, 64));
  if ((t & 63) == 0) redm[t >> 6] = lmax;
  __syncthreads();
  float m = fmaxf(fmaxf(redm[0], redm[1]), fmaxf(redm[2], redm[3]));
  float lsum = 0.f;
  for (int j = t; j < Dd; j += 256) {
    float e = expf(lg[j] - m);
    lg[j] = e;
    lsum += e;
  }
#pragma unroll
  for (int off = 32; off > 0; off >>= 1) lsum += __shfl_down(lsum, off, 64);
  if ((t & 63) == 0) reds[t >> 6] = lsum;
  __syncthreads();
  float inv = 1.f / (reds[0] + reds[1] + reds[2] + reds[3]);
  for (int j = t; j < Dd; j += 256) P[(size_t)i * Dd + j] = f2bf(lg[j] * inv);
}

// K3: PT[j][d] = P[d][j], 64x64 LDS tiles (bf16).
__global__ __launch_bounds__(256) void k_transpose(const unsigned short* __restrict__ P,
                                                   unsigned short* __restrict__ PT) {
  __shared__ unsigned short tile[64][65];
  int tx = threadIdx.x & 63, ty = threadIdx.x >> 6;
  int r0 = blockIdx.y * 64, c0 = blockIdx.x * 64;
#pragma unroll
  for (int r = ty; r < 64; r += 4)
    tile[r][tx] = P[(size_t)(r0 + r) * Dd + c0 + tx];
  __syncthreads();
#pragma unroll
  for (int r = ty; r < 64; r += 4)
    PT[(size_t)(c0 + r) * Dd + r0 + tx] = tile[tx][r];
}

// K4: XT[b][f][d] = bf16(x[b][d][f]), 64x64 LDS tiles per batch.
__global__ __launch_bounds__(256) void k_xt(const float* __restrict__ x,
                                            unsigned short* __restrict__ XT) {
  __shared__ unsigned short tile[64][65];
  int tx = threadIdx.x & 63, ty = threadIdx.x >> 6;
  int d0 = blockIdx.x * 64, f0 = blockIdx.y * 64;
  const float* xb = x + (size_t)blockIdx.z * Dd * Ff;
  unsigned short* xtb = XT + (size_t)blockIdx.z * Ff * Dd;
#pragma unroll
  for (int r = ty; r < 64; r += 4)
    tile[r][tx] = f2bf(xb[(size_t)(d0 + r) * Ff + f0 + tx]);
  __syncthreads();
#pragma unroll
  for (int r = ty; r < 64; r += 4)
    xtb[(size_t)(f0 + r) * Dd + d0 + tx] = tile[tx][r];
}

// K5: batched GEMM. C[b][m][n] = sum_k PT[m][k] * XT[b][n][k].
// m97 structure: 128x128 tile, BK=32, global_load_lds w=16, 16x16x32 bf16 MFMA.
#define BM 128
#define BN 128
#define BK 32

__global__ __launch_bounds__(256) void k_gemm(const unsigned short* __restrict__ PT,
                                              const unsigned short* __restrict__ XT,
                                              float* __restrict__ out) {
  __shared__ unsigned short As[BM * BK];  // [128][32] row-major, 64B rows
  __shared__ unsigned short Bs[BN * BK];
  int t = threadIdx.x;
  int m0 = blockIdx.x * BM;
  int n0 = blockIdx.y * BN;
  const unsigned short* Bsrc = XT + (size_t)blockIdx.z * Ff * Dd;
  float* Cb = out + (size_t)blockIdx.z * Dd * Ff;

  int l = t & 63, w = t >> 6;
  int wm = (w & 1) * 64, wn = (w >> 1) * 64;
  int lm = l & 15, lq = l >> 4;

  floatx4 acc[4][4];
#pragma unroll
  for (int i = 0; i < 4; ++i)
#pragma unroll
    for (int j = 0; j < 4; ++j) acc[i][j] = {0.f, 0.f, 0.f, 0.f};

  // staging: 16B chunk c -> LDS byte offset c*16; row=c/4, k-col=(c%4)*8
  int c0 = t, c1 = t + 256;
  int ar0 = c0 >> 2, ak0 = (c0 & 3) * 8;
  int ar1 = c1 >> 2, ak1 = (c1 & 3) * 8;

  for (int k0 = 0; k0 < Dd; k0 += BK) {
    __syncthreads();  // previous iter's LDS reads done
    gld_lds16(PT + (size_t)(m0 + ar0) * Dd + k0 + ak0, &As[c0 * 8]);
    gld_lds16(PT + (size_t)(m0 + ar1) * Dd + k0 + ak1, &As[c1 * 8]);
    gld_lds16(Bsrc + (size_t)(n0 + ar0) * Dd + k0 + ak0, &Bs[c0 * 8]);
    gld_lds16(Bsrc + (size_t)(n0 + ar1) * Dd + k0 + ak1, &Bs[c1 * 8]);
    __syncthreads();  // drain global_load_lds (vmcnt) + barrier

    short8 a[4], b[4];
#pragma unroll
    for (int mi = 0; mi < 4; ++mi)
      a[mi] = *(const short8*)&As[(wm + mi * 16 + lm) * BK + lq * 8];
#pragma unroll
    for (int ni = 0; ni < 4; ++ni)
      b[ni] = *(const short8*)&Bs[(wn + ni * 16 + lm) * BK + lq * 8];
#pragma unroll
    for (int mi = 0; mi < 4; ++mi)
#pragma unroll
      for (int ni = 0; ni < 4; ++ni)
        acc[mi][ni] = __builtin_amdgcn_mfma_f32_16x16x32_bf16(a[mi], b[ni], acc[mi][ni], 0, 0, 0);
  }

  // epilogue: C/D layout col=lane&15, row=(lane>>4)*4+reg (m89-verified)
#pragma unroll
  for (int mi = 0; mi < 4; ++mi) {
#pragma unroll
    for (int r = 0; r < 4; ++r) {
      int row = m0 + wm + mi * 16 + lq * 4 + r;
#pragma unroll
      for (int ni = 0; ni < 4; ++ni) {
        int col = n0 + wn + ni * 16 + lm;
        Cb[(size_t)row * Ff + col] = acc[mi][ni][r];
      }
    }
  }
}

extern "C" void kernel_launch(void* const* d_in, const int* in_sizes, int n_in,
                              void* d_out, int out_size, void* d_ws, size_t ws_size,
                              hipStream_t stream) {
  const float* x = (const float*)d_in[0];
  const float* s = (const float*)d_in[1];
  float* out = (float*)d_out;

  char* ws = (char*)d_ws;
  float* abs_sum = (float*)ws;                                    // 8 KB
  unsigned short* P  = (unsigned short*)(ws + 8192);              // 8 MB
  unsigned short* PT = (unsigned short*)(ws + 8192 + 8388608);    // 8 MB
  unsigned short* XT = (unsigned short*)(ws + 8192 + 16777216);   // 64 MB
  // total ws use: ~80 MB

  hipMemsetAsync(abs_sum, 0, Dd * sizeof(float), stream);
  k_abs_sum<<<dim3(Dd / 256, Dd / 128), 256, 0, stream>>>(s, abs_sum);
  k_softmax<<<Dd, 256, 0, stream>>>(s, abs_sum, P);
  k_transpose<<<dim3(Dd / 64, Dd / 64), 256, 0, stream>>>(P, PT);
  k_xt<<<dim3(Dd / 64, Ff / 64, Bsz), 256, 0, stream>>>(x, XT);
  k_gemm<<<dim3(Dd / BM, Ff / BN, Bsz), 256, 0, stream>>>(PT, XT, out);
}